// Round 15
// baseline (2183.572 us; speedup 1.0000x reference)
//
#include <hip/hip_runtime.h>
#include <hip/hip_bf16.h>
#include <math.h>

// FactorizedVectorQuantizer MI355X (gfx950) — R15: R13-verified MFMA filter,
// restructured: (a) operands pre-ARRANGED in prep so every global_load_lds is
// per-wave-contiguous 1KB (R14's X gather = 64 lines/inst was the killer);
// (b) 128x128 tile -> acc[4] (64 AGPR), ~124 regs, 4 blocks/CU, 16 waves;
// (c) per-rt incremental epilogue (32 live regs, no scratch spill — R13/R14
// had ~107MB spill WRITE_SIZE).
//
// Soundness (R13-verified, unchanged): exactD/approxD share Sp=(S+t);
// |approxD-exactD| <= Delta ~ 3.4e-5; emit j if approxD_j <= blockMin + THR,
// THR = 1.2e-4 > 2*Delta (block = 128 codes now; each block's true-min row
// candidate still emitted). recheck_k re-evaluates candidates with the proven
// serial-ascending-k fp32 chain; packed-u64 min = numpy lowest-index ties.

#define NROWS   32768
#define NSHAPE  8192
#define NCOLOR  512
#define HALF    128
#define CAPS    184
#define THRF    1.2e-4f
#define NBLK_A  16384               // 256 rowblks x 64 colblks (128 codes each)

// ws byte offsets (<= 856080, proven size)
#define OFF_TS    0u
#define OFF_TC    32768u
#define OFF_CNT_S 34816u
#define OFF_CNT_C 67584u
#define OFF_LOSS  69632u
#define OFF_SS    69648u
#define OFF_SC    200720u
#define OFF_BS    331792u
#define OFF_BC    593936u
#define OFF_WSEND 856080u

// d_out scratch byte offsets — every region read is fully rewritten each
// launch; finalize_k/scalars_k overwrite all of d_out afterwards.
// xhi/xlo arranged: [rowblk 256][slab 8][chunk 256][16B], chunk = kh*128+row.
// whi/wlo arranged: [colblk 64][slab 8][chunk 256][16B], chunk = kh*128+col.
#define OX_HI   0u
#define OX_LO   8388608u
#define OW_HI   16777216u
#define OW_LO   18874368u
#define OC_S    20971520u           // u16[32768*CAPS] = 12,058,624
#define OWCT    33030144u           // f32 Wct[128][512]
#define ORCS    33292288u           // u32[32768] -> ends 33,423,360

typedef __attribute__((address_space(3))) unsigned int  lds_u32;
typedef __attribute__((address_space(1))) const unsigned int gbl_u32;
typedef __attribute__((ext_vector_type(8)))  short short8v;
typedef __attribute__((ext_vector_type(16))) float f32x16;

__device__ __forceinline__ unsigned mono_f32(float d) {
    unsigned u = __float_as_uint(d);
    return (u & 0x80000000u) ? ~u : (u | 0x80000000u);
}
__device__ __forceinline__ unsigned short rne_bf16(float v) {
    unsigned u = __float_as_uint(v);
    unsigned r = u + 0x7FFFu + ((u >> 16) & 1u);
    return (unsigned short)(r >> 16);
}
__device__ __forceinline__ float bf16_f(unsigned short h) {
    return __uint_as_float(((unsigned)h) << 16);
}

// prep: codes_sq(34) | rows_sq(128) | W split+arrange(32) | Wct(32) | X split+arrange(512)
__global__ __launch_bounds__(256) void prep_k(
    const float* __restrict__ Ws, const float* __restrict__ Wc,
    const float* __restrict__ input,
    float* __restrict__ ts, float* __restrict__ tc,
    float* __restrict__ Ss, float* __restrict__ Sc,
    unsigned short* __restrict__ whiG, unsigned short* __restrict__ wloG,
    float* __restrict__ Wct,
    unsigned short* __restrict__ xhi, unsigned short* __restrict__ xlo)
{
    __shared__ float tile[128][65];
    int blk = blockIdx.x, tid = threadIdx.x;
    if (blk < 34) {
        int j = blk * 256 + tid;
        const float* w; int jl;
        if (j < NSHAPE) { w = Ws + (size_t)j * HALF; jl = j; }
        else            { w = Wc + (size_t)(j - NSHAPE) * HALF; jl = j - NSHAPE; }
        float s = 0.f;
        #pragma unroll
        for (int k = 0; k < HALF; ++k) s = fmaf(w[k], w[k], s);
        if (j < NSHAPE) ts[jl] = s; else tc[jl] = s;
    } else if (blk < 162) {
        int r = (blk - 34) * 256 + tid;
        int b = r >> 10, hw = r & 1023;
        const float* __restrict__ xin = input + ((size_t)b << 18) + hw;
        float s = 0.f;
        #pragma unroll
        for (int k = 0; k < HALF; ++k) { float v = xin[(size_t)k << 10]; s = fmaf(v, v, s); }
        Ss[r] = s;
        float s2 = 0.f;
        #pragma unroll
        for (int k = 0; k < HALF; ++k) { float v = xin[(size_t)(k + HALF) << 10]; s2 = fmaf(v, v, s2); }
        Sc[r] = s2;
    } else if (blk < 194) {
        // shape codebook bf16 hi/lo split -> ARRANGED layout
        int blkW = blk - 162;                    // 0..31, 256 codes each
        size_t f0 = ((size_t)blkW) << 15;
        for (int it = 0; it < 32; ++it) {
            size_t g = ((size_t)(it * 256 + tid)) << 2;   // float idx in blk
            size_t fi = f0 + g;
            float4 v = *(const float4*)(Ws + fi);
            int code = (int)(fi >> 7);
            int kk = (int)(fi & 127);            // k start (multiple of 4)
            int cb = code >> 7, cl = code & 127;
            int s = kk >> 4, kh = (kk >> 3) & 1, j4 = (kk >> 2) & 1;
            size_t addr = ((((size_t)cb << 3) + s) * 256
                           + (kh << 7) + cl) * 8 + (j4 << 2);
            unsigned short h0 = rne_bf16(v.x), h1 = rne_bf16(v.y);
            unsigned short h2 = rne_bf16(v.z), h3 = rne_bf16(v.w);
            *(ushort4*)(whiG + addr) = make_ushort4(h0, h1, h2, h3);
            *(ushort4*)(wloG + addr) = make_ushort4(rne_bf16(v.x - bf16_f(h0)),
                                                    rne_bf16(v.y - bf16_f(h1)),
                                                    rne_bf16(v.z - bf16_f(h2)),
                                                    rne_bf16(v.w - bf16_f(h3)));
        }
    } else if (blk < 226) {
        // color codebook fp32 transpose: Wct[k][512]
        int b2 = blk - 194;
        int c0 = (b2 & 7) << 6, k0 = (b2 >> 3) << 5;
        int kk = tid & 31, cc = tid >> 5;
        #pragma unroll
        for (int p = 0; p < 8; ++p) {
            int c = cc + (p << 3);
            tile[kk][c] = Wc[(size_t)(c0 + c) * HALF + k0 + kk];
        }
        __syncthreads();
        int c2 = tid & 63, kr0 = (tid >> 6) << 3;
        #pragma unroll
        for (int p = 0; p < 8; ++p) {
            int kr = kr0 + p;
            Wct[(size_t)(k0 + kr) * 512 + c0 + c2] = tile[kr][c2];
        }
    } else {
        // X shape-half bf16 hi/lo split -> ARRANGED layout
        int rb = blk - 226;                 // 0..511, 64 rows each
        int r0x = rb << 6;
        int b = r0x >> 10, hw0 = r0x & 1023;
        for (int p = 0; p < 32; ++p) {
            int idx = p * 256 + tid;
            int ch = idx >> 6, h2 = idx & 63;
            tile[ch][h2] = input[((size_t)b << 18) + ((size_t)ch << 10) + hw0 + h2];
        }
        __syncthreads();
        int lr = tid >> 2, kc = tid & 3;
        int rowblk = rb >> 1;
        int row127 = ((rb & 1) << 6) + lr;
        #pragma unroll
        for (int p = 0; p < 2; ++p)
            #pragma unroll
            for (int q = 0; q < 2; ++q) {
                int s = kc * 2 + p;
                int k0 = s * 16 + q * 8;
                size_t addr = ((((size_t)rowblk << 3) + s) * 256
                               + (q << 7) + row127) * 8;
                float v0 = tile[k0 + 0][lr], v1 = tile[k0 + 1][lr];
                float v2 = tile[k0 + 2][lr], v3 = tile[k0 + 3][lr];
                float v4 = tile[k0 + 4][lr], v5 = tile[k0 + 5][lr];
                float v6 = tile[k0 + 6][lr], v7 = tile[k0 + 7][lr];
                unsigned short a0 = rne_bf16(v0), a1 = rne_bf16(v1);
                unsigned short a2 = rne_bf16(v2), a3 = rne_bf16(v3);
                unsigned short a4 = rne_bf16(v4), a5 = rne_bf16(v5);
                unsigned short a6 = rne_bf16(v6), a7 = rne_bf16(v7);
                *(ushort4*)(xhi + addr)     = make_ushort4(a0, a1, a2, a3);
                *(ushort4*)(xhi + addr + 4) = make_ushort4(a4, a5, a6, a7);
                *(ushort4*)(xlo + addr)     = make_ushort4(rne_bf16(v0 - bf16_f(a0)),
                                                           rne_bf16(v1 - bf16_f(a1)),
                                                           rne_bf16(v2 - bf16_f(a2)),
                                                           rne_bf16(v3 - bf16_f(a3)));
                *(ushort4*)(xlo + addr + 4) = make_ushort4(rne_bf16(v4 - bf16_f(a4)),
                                                           rne_bf16(v5 - bf16_f(a5)),
                                                           rne_bf16(v6 - bf16_f(a6)),
                                                           rne_bf16(v7 - bf16_f(a7)));
            }
    }
}

// ---- approx MFMA filter: block = 128 rows x 128 shape codes ----
__global__ __launch_bounds__(256, 4) void approx_k(
    const unsigned short* __restrict__ xarrH, const unsigned short* __restrict__ xarrL,
    const unsigned short* __restrict__ warrH, const unsigned short* __restrict__ warrL,
    const float* __restrict__ ts, const float* __restrict__ Ss,
    unsigned* __restrict__ rcS, unsigned short* __restrict__ candS)
{
    __shared__ __align__(16) char smem[32768];
    // per 16KB buffer: XH 4K | XL 4K @4096 | WH 4K @8192 | WL 4K @12288
    // chunk = kh*128 + idx (idx = row for X, col for W) -> conflict-free reads

    int d = blockIdx.x;
    int o = (d & 7) * 2048 + (d >> 3);          // bijective XCD swizzle
    int rowblk = o >> 6, colblk = o & 63;
    int cg0 = colblk << 7;
    int r0 = rowblk << 7;

    int tid = threadIdx.x;
    int lane = tid & 63;
    int wv = __builtin_amdgcn_readfirstlane(tid >> 6);
    int l31 = lane & 31, lh = lane >> 5;

    // per-wave-contiguous DMA sources (arranged layouts)
    size_t xoff = (((size_t)rowblk << 11) + wv * 64 + lane) * 8;   // rowblk*8*256
    const unsigned short* xsrcH = xarrH + xoff;
    const unsigned short* xsrcL = xarrL + xoff;
    size_t woff = (((size_t)colblk << 11) + wv * 64 + lane) * 8;
    const unsigned short* wsrcH = warrH + woff;
    const unsigned short* wsrcL = warrL + woff;

#define STG(s, buf) { char* bb = smem + (buf) * 16384; size_t ko = (size_t)(s) * 2048; \
    __builtin_amdgcn_global_load_lds((gbl_u32*)(xsrcH + ko), (lds_u32*)(bb + wv * 1024), 16, 0, 0); \
    __builtin_amdgcn_global_load_lds((gbl_u32*)(xsrcL + ko), (lds_u32*)(bb + 4096 + wv * 1024), 16, 0, 0); \
    __builtin_amdgcn_global_load_lds((gbl_u32*)(wsrcH + ko), (lds_u32*)(bb + 8192 + wv * 1024), 16, 0, 0); \
    __builtin_amdgcn_global_load_lds((gbl_u32*)(wsrcL + ko), (lds_u32*)(bb + 12288 + wv * 1024), 16, 0, 0); }

    f32x16 acc[4];
    #pragma unroll
    for (int rt = 0; rt < 4; ++rt)
        #pragma unroll
        for (int e = 0; e < 16; ++e) acc[rt][e] = 0.f;

    STG(0, 0);
    __syncthreads();

    for (int ks = 0; ks < 8; ++ks) {
        if (ks < 7) STG(ks + 1, (ks + 1) & 1);   // issue-early prefetch

        const char* bb = smem + (ks & 1) * 16384;
        const short8v* XH = (const short8v*)bb;
        const short8v* XL = (const short8v*)(bb + 4096);
        const short8v* WH = (const short8v*)(bb + 8192);
        const short8v* WL = (const short8v*)(bb + 12288);
        short8v Bh = WH[lh * 128 + wv * 32 + l31];
        short8v Bl = WL[lh * 128 + wv * 32 + l31];
        #pragma unroll
        for (int rt = 0; rt < 4; ++rt) {
            short8v Ah = XH[lh * 128 + rt * 32 + l31];
            short8v Al = XL[lh * 128 + rt * 32 + l31];
            acc[rt] = __builtin_amdgcn_mfma_f32_32x32x16_bf16(Ah, Bh, acc[rt], 0, 0, 0);
            acc[rt] = __builtin_amdgcn_mfma_f32_32x32x16_bf16(Ah, Bl, acc[rt], 0, 0, 0);
            acc[rt] = __builtin_amdgcn_mfma_f32_32x32x16_bf16(Al, Bh, acc[rt], 0, 0, 0);
        }
        __syncthreads();   // drains prefetch DMA; frees buf[ks&1] for ks+2
    }

    // ---- epilogue: per-rt incremental min/threshold/emit (32 live regs) ----
    float* red    = (float*)smem;              // [32][4]
    float* rowthr = (float*)(smem + 512);      // [32]
    float* sld    = (float*)(smem + 1024);     // [128]
    if (tid < 128) sld[tid] = Ss[r0 + tid];
    float tcol = ts[cg0 + wv * 32 + l31];
    __syncthreads();

    for (int rt = 0; rt < 4; ++rt) {
        float dm[16], bm[16];
        #pragma unroll
        for (int q = 0; q < 16; ++q) {
            int rrl = (q & 3) + 8 * (q >> 2) + 4 * lh;
            dm[q] = fmaf(-2.0f, acc[rt][q], sld[rt * 32 + rrl] + tcol);
            bm[q] = dm[q];
        }
        #pragma unroll
        for (int m = 1; m < 32; m <<= 1)
            #pragma unroll
            for (int q = 0; q < 16; ++q)
                bm[q] = fminf(bm[q], __shfl_xor(bm[q], m, 64));
        if (l31 == 0) {
            #pragma unroll
            for (int q = 0; q < 16; ++q)
                red[((q & 3) + 8 * (q >> 2) + 4 * lh) * 4 + wv] = bm[q];
        }
        __syncthreads();
        if (tid < 32)
            rowthr[tid] = fminf(fminf(red[tid * 4 + 0], red[tid * 4 + 1]),
                                fminf(red[tid * 4 + 2], red[tid * 4 + 3])) + THRF;
        __syncthreads();
        #pragma unroll
        for (int q = 0; q < 16; ++q) {
            int rrl = (q & 3) + 8 * (q >> 2) + 4 * lh;
            if (dm[q] <= rowthr[rrl]) {
                int rr = r0 + rt * 32 + rrl;
                unsigned idx = atomicAdd(&rcS[rr], 1u);
                if (idx < CAPS)
                    candS[(size_t)rr * CAPS + idx] =
                        (unsigned short)(cg0 + wv * 32 + l31);
            }
        }
        __syncthreads();   // red/rowthr reuse next rt
    }
}

// ---- color: exact fp32 GEMM argmin (R8-proven, unchanged) ----
#define FMA_ROW(i, xv) \
    acc[i][0] = fmaf(xv, w0.x, acc[i][0]); acc[i][1] = fmaf(xv, w0.y, acc[i][1]); \
    acc[i][2] = fmaf(xv, w0.z, acc[i][2]); acc[i][3] = fmaf(xv, w0.w, acc[i][3]); \
    acc[i][4] = fmaf(xv, w1.x, acc[i][4]); acc[i][5] = fmaf(xv, w1.y, acc[i][5]); \
    acc[i][6] = fmaf(xv, w1.z, acc[i][6]); acc[i][7] = fmaf(xv, w1.w, acc[i][7]);

__global__ __launch_bounds__(256, 4) void color_exact_k(
    const float* __restrict__ input, const float* __restrict__ wct,
    const float* __restrict__ tc, const float* __restrict__ Sc,
    unsigned long long* __restrict__ bc)
{
    __shared__ __align__(16) char smem[32768];
    float (*xs2)[16][128] = reinterpret_cast<float(*)[16][128]>(smem);
    float (*ws2)[16][128] = reinterpret_cast<float(*)[16][128]>(smem + 16384);

    int d = blockIdx.x;
    int o = (d & 7) * 128 + (d >> 3);
    int rowblk = o >> 2, cb = o & 3;
    int c0 = cb << 7;
    int tid = threadIdx.x;
    int lane = tid & 63;
    int wv = __builtin_amdgcn_readfirstlane(tid >> 6);
    int r0 = rowblk << 7;
    int b = r0 >> 10, hw0 = r0 & 1023;

    const float* __restrict__ xg =
        input + ((size_t)b << 18) + ((size_t)HALF << 10) + hw0
              + ((size_t)(lane >> 5) << 10) + ((lane & 31) << 2);
    const float* __restrict__ wg =
        wct + (size_t)(lane >> 5) * 512 + c0 + ((lane & 31) << 2);

    int tr = tid & 15, tcg = tid >> 4;
    int tr4 = tr << 2, tc4 = tcg << 2;
    int kw = wv << 2;

    float acc[8][8] = {{0.f}};

    #pragma unroll
    for (int i = 0; i < 2; ++i) {
        int kx = kw + (i << 1);
        __builtin_amdgcn_global_load_lds(
            (gbl_u32*)(xg + ((size_t)kx << 10)), (lds_u32*)&xs2[0][kx][0], 16, 0, 0);
        __builtin_amdgcn_global_load_lds(
            (gbl_u32*)(wg + (size_t)kx * 512), (lds_u32*)&ws2[0][kx][0], 16, 0, 0);
    }
    __syncthreads();

    for (int s = 0; s < 8; ++s) {
        if (s < 7) {
            int k0 = (s + 1) << 4;
            #pragma unroll
            for (int i = 0; i < 2; ++i) {
                int kx = kw + (i << 1);
                __builtin_amdgcn_global_load_lds(
                    (gbl_u32*)(xg + ((size_t)(k0 + kx) << 10)),
                    (lds_u32*)&xs2[(s + 1) & 1][kx][0], 16, 0, 0);
                __builtin_amdgcn_global_load_lds(
                    (gbl_u32*)(wg + (size_t)(k0 + kx) * 512),
                    (lds_u32*)&ws2[(s + 1) & 1][kx][0], 16, 0, 0);
            }
        }
        const float (*xsb)[128] = xs2[s & 1];
        const float (*wtb)[128] = ws2[s & 1];
        #pragma unroll 8
        for (int k = 0; k < 16; ++k) {
            const float4 x0 = *(const float4*)&xsb[k][tr4];
            const float4 x1 = *(const float4*)&xsb[k][64 + tr4];
            const float4 w0 = *(const float4*)&wtb[k][tc4];
            const float4 w1 = *(const float4*)&wtb[k][64 + tc4];
            FMA_ROW(0, x0.x) FMA_ROW(1, x0.y) FMA_ROW(2, x0.z) FMA_ROW(3, x0.w)
            FMA_ROW(4, x1.x) FMA_ROW(5, x1.y) FMA_ROW(6, x1.z) FMA_ROW(7, x1.w)
        }
        __syncthreads();
    }

    float Sr[8];
    #pragma unroll
    for (int i = 0; i < 8; ++i) {
        int rl = ((i & 4) << 4) + tr4 + (i & 3);
        Sr[i] = Sc[r0 + rl];
    }
    float bestD[8]; int bestC[8];
    #pragma unroll
    for (int i = 0; i < 8; ++i) { bestD[i] = INFINITY; bestC[i] = 0; }
    #pragma unroll
    for (int j = 0; j < 8; ++j) {
        int cl = ((j & 4) << 4) + tc4 + (j & 3);
        int cgj = c0 + cl;
        float tj = tc[cgj];
        #pragma unroll
        for (int i = 0; i < 8; ++i) {
            float Sp = Sr[i] + tj;
            float D = fmaf(-2.0f, acc[i][j], Sp);
            if (D < bestD[i]) { bestD[i] = D; bestC[i] = cgj; }
        }
    }
    __syncthreads();
    unsigned long long* red = reinterpret_cast<unsigned long long*>(smem);
    #pragma unroll
    for (int i = 0; i < 8; ++i) {
        int rl = ((i & 4) << 4) + tr4 + (i & 3);
        red[rl * 17 + tcg] =
            ((unsigned long long)mono_f32(bestD[i]) << 32) | (unsigned)bestC[i];
    }
    __syncthreads();
    if (tid < 128) {
        unsigned long long m = red[tid * 17];
        #pragma unroll
        for (int q = 1; q < 16; ++q) {
            unsigned long long v = red[tid * 17 + q];
            if (v < m) m = v;
        }
        atomicMin(&bc[r0 + tid], m);
    }
}

// ---- exact recheck of shape candidates (proven fp32 pipeline) ----
__global__ __launch_bounds__(256) void recheck_k(
    const float* __restrict__ input, const float* __restrict__ Ws,
    const float* __restrict__ ts, const float* __restrict__ Ss,
    const unsigned* __restrict__ rcS, const unsigned short* __restrict__ candS,
    unsigned long long* __restrict__ bs)
{
    __shared__ float xsh[32][132];
    int r0b = blockIdx.x << 5;
    int tid = threadIdx.x;
    int b = r0b >> 10, hw0 = r0b & 1023;
    for (int pass = 0; pass < 16; ++pass) {
        int k = pass * 8 + (tid >> 5), rl = tid & 31;
        xsh[rl][k] = input[((size_t)b << 18) + ((size_t)k << 10) + hw0 + rl];
    }
    __syncthreads();
    int g = tid >> 3, j8 = tid & 7;
    int r = r0b + g;
    unsigned n = rcS[r];
    bool full = (n == 0u) || (n > CAPS);
    int ne = full ? NSHAPE : (int)n;
    float Sv = Ss[r];
    const float4* x4 = (const float4*)&xsh[g][0];
    unsigned long long best = ~0ull;
    for (int c = j8; c < ne; c += 8) {
        int code = full ? c : (int)candS[(size_t)r * CAPS + c];
        const float4* w4 = (const float4*)(Ws + ((size_t)code << 7));
        float a = 0.f;
        #pragma unroll
        for (int q = 0; q < 32; ++q) {      // serial ascending-k fp32 chain
            float4 xq = x4[q];
            float4 wq = w4[q];
            a = fmaf(xq.x, wq.x, a); a = fmaf(xq.y, wq.y, a);
            a = fmaf(xq.z, wq.z, a); a = fmaf(xq.w, wq.w, a);
        }
        float D = fmaf(-2.0f, a, Sv + ts[code]);
        unsigned long long p = ((unsigned long long)mono_f32(D) << 32) | (unsigned)code;
        if (p < best) best = p;
    }
    #pragma unroll
    for (int m = 1; m < 8; m <<= 1) {
        unsigned long long v = __shfl_xor(best, m, 64);
        if (v < best) best = v;
    }
    if (j8 == 0) bs[r] = best;
}

__global__ __launch_bounds__(256) void finalize_k(
    const float* __restrict__ input,
    const float* __restrict__ Ws, const float* __restrict__ Wc,
    const unsigned long long* __restrict__ bs,
    const unsigned long long* __restrict__ bc,
    unsigned* __restrict__ cnt_s, unsigned* __restrict__ cnt_c,
    double* __restrict__ loss_sum, float* __restrict__ out)
{
    int tid = threadIdx.x;
    int r = blockIdx.x * 256 + tid;
    int bi = (int)(bs[r] & 0xFFFFFFFFu);
    int ci = (int)(bc[r] & 0xFFFFFFFFu);
    atomicAdd(&cnt_s[bi], 1u);
    atomicAdd(&cnt_c[ci], 1u);

    int b = r >> 10; int hw = r & 1023;
    const float* __restrict__ xin = input + ((size_t)b << 18) + hw;
    float* __restrict__ op = out + ((size_t)b << 18) + hw;
    const float* __restrict__ qs = Ws + ((size_t)bi << 7);
    const float* __restrict__ qc = Wc + ((size_t)ci << 7);

    double ls = 0.0;
    #pragma unroll 8
    for (int c = 0; c < HALF; ++c) {
        float f = xin[(size_t)c << 10];
        float dd = qs[c] - f;                  // fp32(q - f)
        op[(size_t)c << 10] = f + dd;          // fp32(f + fp32(q - f))
        ls += (double)dd * (double)dd;
    }
    #pragma unroll 8
    for (int c = 0; c < HALF; ++c) {
        float f = xin[(size_t)(c + HALF) << 10];
        float dd = qc[c] - f;
        op[(size_t)(c + HALF) << 10] = f + dd;
        ls += (double)dd * (double)dd;
    }
    __shared__ double red[256];
    red[tid] = ls;
    __syncthreads();
    for (int s = 128; s > 0; s >>= 1) {
        if (tid < s) red[tid] += red[tid + s];
        __syncthreads();
    }
    if (tid == 0) atomicAdd(loss_sum, red[0]);
}

__global__ __launch_bounds__(256) void scalars_k(
    const unsigned* __restrict__ cnt_s, const unsigned* __restrict__ cnt_c,
    const double* __restrict__ loss_sum, float* __restrict__ out3)
{
    int tid = threadIdx.x;
    double es = 0.0, ec = 0.0;
    for (int j = tid; j < NSHAPE; j += 256) {
        float p = (float)cnt_s[j] / 32768.0f;
        es += (double)(p * logf(p + 1e-10f));
    }
    for (int j = tid; j < NCOLOR; j += 256) {
        float p = (float)cnt_c[j] / 32768.0f;
        ec += (double)(p * logf(p + 1e-10f));
    }
    __shared__ double r1[256], r2[256];
    r1[tid] = es; r2[tid] = ec;
    __syncthreads();
    for (int s = 128; s > 0; s >>= 1) {
        if (tid < s) { r1[tid] += r1[tid + s]; r2[tid] += r2[tid + s]; }
        __syncthreads();
    }
    if (tid == 0) {
        out3[0] = (float)(1.25 * loss_sum[0] / 8388608.0);
        out3[1] = expf(-(float)r1[0]);
        out3[2] = expf(-(float)r2[0]);
    }
}

extern "C" void kernel_launch(void* const* d_in, const int* in_sizes, int n_in,
                              void* d_out, int out_size, void* d_ws, size_t ws_size,
                              hipStream_t stream)
{
    const float* input = (const float*)d_in[0];
    const float* Ws    = (const float*)d_in[1];
    const float* Wc    = (const float*)d_in[2];
    float* out = (float*)d_out;
    char* ws = (char*)d_ws;
    char* ob = (char*)d_out;

    float*    ts       = (float*)(ws + OFF_TS);
    float*    tcx      = (float*)(ws + OFF_TC);
    unsigned* cnt_s    = (unsigned*)(ws + OFF_CNT_S);
    unsigned* cnt_c    = (unsigned*)(ws + OFF_CNT_C);
    double*   loss_sum = (double*)(ws + OFF_LOSS);
    float*    Ss       = (float*)(ws + OFF_SS);
    float*    Sc       = (float*)(ws + OFF_SC);
    unsigned long long* bs = (unsigned long long*)(ws + OFF_BS);
    unsigned long long* bc = (unsigned long long*)(ws + OFF_BC);

    unsigned short* xhi  = (unsigned short*)(ob + OX_HI);
    unsigned short* xlo  = (unsigned short*)(ob + OX_LO);
    unsigned short* whiG = (unsigned short*)(ob + OW_HI);
    unsigned short* wloG = (unsigned short*)(ob + OW_LO);
    unsigned short* candS = (unsigned short*)(ob + OC_S);
    float*          Wct   = (float*)(ob + OWCT);
    unsigned*       rcS   = (unsigned*)(ob + ORCS);

    hipMemsetAsync(ws + OFF_CNT_S, 0, (OFF_LOSS + 8u) - OFF_CNT_S, stream);
    hipMemsetAsync(ws + OFF_BS, 0xFF, OFF_WSEND - OFF_BS, stream);
    hipMemsetAsync(ob + ORCS, 0, 131072u, stream);

    prep_k<<<738, 256, 0, stream>>>(Ws, Wc, input, ts, tcx, Ss, Sc,
                                    whiG, wloG, Wct, xhi, xlo);

    approx_k<<<NBLK_A, 256, 0, stream>>>(xhi, xlo, whiG, wloG, ts, Ss, rcS, candS);

    color_exact_k<<<1024, 256, 0, stream>>>(input, Wct, tcx, Sc, bc);

    recheck_k<<<1024, 256, 0, stream>>>(input, Ws, ts, Ss, rcS, candS, bs);

    finalize_k<<<NROWS / 256, 256, 0, stream>>>(
        input, Ws, Wc, bs, bc, cnt_s, cnt_c, loss_sum, out);

    scalars_k<<<1, 256, 0, stream>>>(cnt_s, cnt_c, loss_sum, out + 8388608);
}

// Round 16
// 1751.884 us; speedup vs baseline: 1.2464x; 1.2464x over previous
//
#include <hip/hip_runtime.h>
#include <hip/hip_bf16.h>
#include <math.h>

// FactorizedVectorQuantizer MI355X (gfx950) — R16: R15 with the accumulator
// spill fixed (rule #20): acc[4] runtime-indexed in the non-unrolled epilogue
// loop sent all 64 acc floats to scratch (VGPR=48, WRITE_SIZE=8.8GB, approx
// became scratch-BW-bound). Now acc0..acc3 are NAMED registers and the
// epilogue is macro-expanded per rt — zero runtime indexing anywhere.
//
// Soundness (R13-verified, unchanged): exactD/approxD share Sp=(S+t);
// |approxD-exactD| <= Delta ~ 3.4e-5; emit j if approxD_j <= blockMin + THR,
// THR = 1.2e-4 > 2*Delta. recheck_k re-evaluates candidates with the proven
// serial-ascending-k fp32 chain; packed-u64 min = numpy lowest-index ties.

#define NROWS   32768
#define NSHAPE  8192
#define NCOLOR  512
#define HALF    128
#define CAPS    184
#define THRF    1.2e-4f
#define NBLK_A  16384               // 256 rowblks x 64 colblks (128 codes each)

// ws byte offsets (<= 856080, proven size)
#define OFF_TS    0u
#define OFF_TC    32768u
#define OFF_CNT_S 34816u
#define OFF_CNT_C 67584u
#define OFF_LOSS  69632u
#define OFF_SS    69648u
#define OFF_SC    200720u
#define OFF_BS    331792u
#define OFF_BC    593936u
#define OFF_WSEND 856080u

// d_out scratch byte offsets — every region read is fully rewritten each
// launch; finalize_k/scalars_k overwrite all of d_out afterwards.
// xhi/xlo arranged: [rowblk 256][slab 8][chunk 256][16B], chunk = kh*128+row.
// whi/wlo arranged: [colblk 64][slab 8][chunk 256][16B], chunk = kh*128+col.
#define OX_HI   0u
#define OX_LO   8388608u
#define OW_HI   16777216u
#define OW_LO   18874368u
#define OC_S    20971520u           // u16[32768*CAPS] = 12,058,624
#define OWCT    33030144u           // f32 Wct[128][512]
#define ORCS    33292288u           // u32[32768] -> ends 33,423,360

typedef __attribute__((address_space(3))) unsigned int  lds_u32;
typedef __attribute__((address_space(1))) const unsigned int gbl_u32;
typedef __attribute__((ext_vector_type(8)))  short short8v;
typedef __attribute__((ext_vector_type(16))) float f32x16;

__device__ __forceinline__ unsigned mono_f32(float d) {
    unsigned u = __float_as_uint(d);
    return (u & 0x80000000u) ? ~u : (u | 0x80000000u);
}
__device__ __forceinline__ unsigned short rne_bf16(float v) {
    unsigned u = __float_as_uint(v);
    unsigned r = u + 0x7FFFu + ((u >> 16) & 1u);
    return (unsigned short)(r >> 16);
}
__device__ __forceinline__ float bf16_f(unsigned short h) {
    return __uint_as_float(((unsigned)h) << 16);
}

// prep: codes_sq(34) | rows_sq(128) | W split+arrange(32) | Wct(32) | X split+arrange(512)
__global__ __launch_bounds__(256) void prep_k(
    const float* __restrict__ Ws, const float* __restrict__ Wc,
    const float* __restrict__ input,
    float* __restrict__ ts, float* __restrict__ tc,
    float* __restrict__ Ss, float* __restrict__ Sc,
    unsigned short* __restrict__ whiG, unsigned short* __restrict__ wloG,
    float* __restrict__ Wct,
    unsigned short* __restrict__ xhi, unsigned short* __restrict__ xlo)
{
    __shared__ float tile[128][65];
    int blk = blockIdx.x, tid = threadIdx.x;
    if (blk < 34) {
        int j = blk * 256 + tid;
        const float* w; int jl;
        if (j < NSHAPE) { w = Ws + (size_t)j * HALF; jl = j; }
        else            { w = Wc + (size_t)(j - NSHAPE) * HALF; jl = j - NSHAPE; }
        float s = 0.f;
        #pragma unroll
        for (int k = 0; k < HALF; ++k) s = fmaf(w[k], w[k], s);
        if (j < NSHAPE) ts[jl] = s; else tc[jl] = s;
    } else if (blk < 162) {
        int r = (blk - 34) * 256 + tid;
        int b = r >> 10, hw = r & 1023;
        const float* __restrict__ xin = input + ((size_t)b << 18) + hw;
        float s = 0.f;
        #pragma unroll
        for (int k = 0; k < HALF; ++k) { float v = xin[(size_t)k << 10]; s = fmaf(v, v, s); }
        Ss[r] = s;
        float s2 = 0.f;
        #pragma unroll
        for (int k = 0; k < HALF; ++k) { float v = xin[(size_t)(k + HALF) << 10]; s2 = fmaf(v, v, s2); }
        Sc[r] = s2;
    } else if (blk < 194) {
        // shape codebook bf16 hi/lo split -> ARRANGED layout
        int blkW = blk - 162;                    // 0..31, 256 codes each
        size_t f0 = ((size_t)blkW) << 15;
        for (int it = 0; it < 32; ++it) {
            size_t g = ((size_t)(it * 256 + tid)) << 2;   // float idx in blk
            size_t fi = f0 + g;
            float4 v = *(const float4*)(Ws + fi);
            int code = (int)(fi >> 7);
            int kk = (int)(fi & 127);            // k start (multiple of 4)
            int cb = code >> 7, cl = code & 127;
            int s = kk >> 4, kh = (kk >> 3) & 1, j4 = (kk >> 2) & 1;
            size_t addr = ((((size_t)cb << 3) + s) * 256
                           + (kh << 7) + cl) * 8 + (j4 << 2);
            unsigned short h0 = rne_bf16(v.x), h1 = rne_bf16(v.y);
            unsigned short h2 = rne_bf16(v.z), h3 = rne_bf16(v.w);
            *(ushort4*)(whiG + addr) = make_ushort4(h0, h1, h2, h3);
            *(ushort4*)(wloG + addr) = make_ushort4(rne_bf16(v.x - bf16_f(h0)),
                                                    rne_bf16(v.y - bf16_f(h1)),
                                                    rne_bf16(v.z - bf16_f(h2)),
                                                    rne_bf16(v.w - bf16_f(h3)));
        }
    } else if (blk < 226) {
        // color codebook fp32 transpose: Wct[k][512]
        int b2 = blk - 194;
        int c0 = (b2 & 7) << 6, k0 = (b2 >> 3) << 5;
        int kk = tid & 31, cc = tid >> 5;
        #pragma unroll
        for (int p = 0; p < 8; ++p) {
            int c = cc + (p << 3);
            tile[kk][c] = Wc[(size_t)(c0 + c) * HALF + k0 + kk];
        }
        __syncthreads();
        int c2 = tid & 63, kr0 = (tid >> 6) << 3;
        #pragma unroll
        for (int p = 0; p < 8; ++p) {
            int kr = kr0 + p;
            Wct[(size_t)(k0 + kr) * 512 + c0 + c2] = tile[kr][c2];
        }
    } else {
        // X shape-half bf16 hi/lo split -> ARRANGED layout
        int rb = blk - 226;                 // 0..511, 64 rows each
        int r0x = rb << 6;
        int b = r0x >> 10, hw0 = r0x & 1023;
        for (int p = 0; p < 32; ++p) {
            int idx = p * 256 + tid;
            int ch = idx >> 6, h2 = idx & 63;
            tile[ch][h2] = input[((size_t)b << 18) + ((size_t)ch << 10) + hw0 + h2];
        }
        __syncthreads();
        int lr = tid >> 2, kc = tid & 3;
        int rowblk = rb >> 1;
        int row127 = ((rb & 1) << 6) + lr;
        #pragma unroll
        for (int p = 0; p < 2; ++p)
            #pragma unroll
            for (int q = 0; q < 2; ++q) {
                int s = kc * 2 + p;
                int k0 = s * 16 + q * 8;
                size_t addr = ((((size_t)rowblk << 3) + s) * 256
                               + (q << 7) + row127) * 8;
                float v0 = tile[k0 + 0][lr], v1 = tile[k0 + 1][lr];
                float v2 = tile[k0 + 2][lr], v3 = tile[k0 + 3][lr];
                float v4 = tile[k0 + 4][lr], v5 = tile[k0 + 5][lr];
                float v6 = tile[k0 + 6][lr], v7 = tile[k0 + 7][lr];
                unsigned short a0 = rne_bf16(v0), a1 = rne_bf16(v1);
                unsigned short a2 = rne_bf16(v2), a3 = rne_bf16(v3);
                unsigned short a4 = rne_bf16(v4), a5 = rne_bf16(v5);
                unsigned short a6 = rne_bf16(v6), a7 = rne_bf16(v7);
                *(ushort4*)(xhi + addr)     = make_ushort4(a0, a1, a2, a3);
                *(ushort4*)(xhi + addr + 4) = make_ushort4(a4, a5, a6, a7);
                *(ushort4*)(xlo + addr)     = make_ushort4(rne_bf16(v0 - bf16_f(a0)),
                                                           rne_bf16(v1 - bf16_f(a1)),
                                                           rne_bf16(v2 - bf16_f(a2)),
                                                           rne_bf16(v3 - bf16_f(a3)));
                *(ushort4*)(xlo + addr + 4) = make_ushort4(rne_bf16(v4 - bf16_f(a4)),
                                                           rne_bf16(v5 - bf16_f(a5)),
                                                           rne_bf16(v6 - bf16_f(a6)),
                                                           rne_bf16(v7 - bf16_f(a7)));
            }
    }
}

// ---- approx MFMA filter: block = 128 rows x 128 shape codes ----
__global__ __launch_bounds__(256, 4) void approx_k(
    const unsigned short* __restrict__ xarrH, const unsigned short* __restrict__ xarrL,
    const unsigned short* __restrict__ warrH, const unsigned short* __restrict__ warrL,
    const float* __restrict__ ts, const float* __restrict__ Ss,
    unsigned* __restrict__ rcS, unsigned short* __restrict__ candS)
{
    __shared__ __align__(16) char smem[32768];
    // per 16KB buffer: XH 4K | XL 4K @4096 | WH 4K @8192 | WL 4K @12288
    // chunk = kh*128 + idx (idx = row for X, col for W) -> conflict-free reads

    int d = blockIdx.x;
    int o = (d & 7) * 2048 + (d >> 3);          // bijective XCD swizzle
    int rowblk = o >> 6, colblk = o & 63;
    int cg0 = colblk << 7;
    int r0 = rowblk << 7;

    int tid = threadIdx.x;
    int lane = tid & 63;
    int wv = __builtin_amdgcn_readfirstlane(tid >> 6);
    int l31 = lane & 31, lh = lane >> 5;

    // per-wave-contiguous DMA sources (arranged layouts)
    size_t xoff = (((size_t)rowblk << 11) + wv * 64 + lane) * 8;
    const unsigned short* xsrcH = xarrH + xoff;
    const unsigned short* xsrcL = xarrL + xoff;
    size_t woff = (((size_t)colblk << 11) + wv * 64 + lane) * 8;
    const unsigned short* wsrcH = warrH + woff;
    const unsigned short* wsrcL = warrL + woff;

#define STG(s, buf) { char* bb = smem + (buf) * 16384; size_t ko = (size_t)(s) * 2048; \
    __builtin_amdgcn_global_load_lds((gbl_u32*)(xsrcH + ko), (lds_u32*)(bb + wv * 1024), 16, 0, 0); \
    __builtin_amdgcn_global_load_lds((gbl_u32*)(xsrcL + ko), (lds_u32*)(bb + 4096 + wv * 1024), 16, 0, 0); \
    __builtin_amdgcn_global_load_lds((gbl_u32*)(wsrcH + ko), (lds_u32*)(bb + 8192 + wv * 1024), 16, 0, 0); \
    __builtin_amdgcn_global_load_lds((gbl_u32*)(wsrcL + ko), (lds_u32*)(bb + 12288 + wv * 1024), 16, 0, 0); }

    // NAMED accumulators — no array, no runtime indexing (rule #20)
    f32x16 acc0, acc1, acc2, acc3;
    #pragma unroll
    for (int e = 0; e < 16; ++e) { acc0[e] = 0.f; acc1[e] = 0.f; acc2[e] = 0.f; acc3[e] = 0.f; }

    STG(0, 0);
    __syncthreads();

    for (int ks = 0; ks < 8; ++ks) {
        if (ks < 7) STG(ks + 1, (ks + 1) & 1);   // issue-early prefetch

        const char* bb = smem + (ks & 1) * 16384;
        const short8v* XH = (const short8v*)bb;
        const short8v* XL = (const short8v*)(bb + 4096);
        const short8v* WH = (const short8v*)(bb + 8192);
        const short8v* WL = (const short8v*)(bb + 12288);
        short8v Bh = WH[lh * 128 + wv * 32 + l31];
        short8v Bl = WL[lh * 128 + wv * 32 + l31];
#define MFMA_RT(rt, accv) { \
        short8v Ah = XH[lh * 128 + (rt) * 32 + l31]; \
        short8v Al = XL[lh * 128 + (rt) * 32 + l31]; \
        accv = __builtin_amdgcn_mfma_f32_32x32x16_bf16(Ah, Bh, accv, 0, 0, 0); \
        accv = __builtin_amdgcn_mfma_f32_32x32x16_bf16(Ah, Bl, accv, 0, 0, 0); \
        accv = __builtin_amdgcn_mfma_f32_32x32x16_bf16(Al, Bh, accv, 0, 0, 0); }
        MFMA_RT(0, acc0) MFMA_RT(1, acc1) MFMA_RT(2, acc2) MFMA_RT(3, acc3)
        __syncthreads();   // drains prefetch DMA; frees buf[ks&1] for ks+2
    }

    // ---- epilogue: per-rt macro-expanded min/threshold/emit ----
    float* red    = (float*)smem;              // [32][4]
    float* rowthr = (float*)(smem + 512);      // [32]
    float* sld    = (float*)(smem + 1024);     // [128]
    if (tid < 128) sld[tid] = Ss[r0 + tid];
    float tcol = ts[cg0 + wv * 32 + l31];
    __syncthreads();

#define EPI_RT(rt, accv) { \
    float dm[16], bm[16]; \
    _Pragma("unroll") \
    for (int q = 0; q < 16; ++q) { \
        int rrl = (q & 3) + 8 * (q >> 2) + 4 * lh; \
        dm[q] = fmaf(-2.0f, accv[q], sld[(rt) * 32 + rrl] + tcol); \
        bm[q] = dm[q]; \
    } \
    _Pragma("unroll") \
    for (int m = 1; m < 32; m <<= 1) { \
        _Pragma("unroll") \
        for (int q = 0; q < 16; ++q) \
            bm[q] = fminf(bm[q], __shfl_xor(bm[q], m, 64)); \
    } \
    if (l31 == 0) { \
        _Pragma("unroll") \
        for (int q = 0; q < 16; ++q) \
            red[((q & 3) + 8 * (q >> 2) + 4 * lh) * 4 + wv] = bm[q]; \
    } \
    __syncthreads(); \
    if (tid < 32) \
        rowthr[tid] = fminf(fminf(red[tid * 4 + 0], red[tid * 4 + 1]), \
                            fminf(red[tid * 4 + 2], red[tid * 4 + 3])) + THRF; \
    __syncthreads(); \
    _Pragma("unroll") \
    for (int q = 0; q < 16; ++q) { \
        int rrl = (q & 3) + 8 * (q >> 2) + 4 * lh; \
        if (dm[q] <= rowthr[rrl]) { \
            int rr = r0 + (rt) * 32 + rrl; \
            unsigned idx = atomicAdd(&rcS[rr], 1u); \
            if (idx < CAPS) \
                candS[(size_t)rr * CAPS + idx] = \
                    (unsigned short)(cg0 + wv * 32 + l31); \
        } \
    } \
    __syncthreads(); }

    EPI_RT(0, acc0) EPI_RT(1, acc1) EPI_RT(2, acc2) EPI_RT(3, acc3)
}

// ---- color: exact fp32 GEMM argmin (R8-proven, unchanged) ----
#define FMA_ROW(i, xv) \
    acc[i][0] = fmaf(xv, w0.x, acc[i][0]); acc[i][1] = fmaf(xv, w0.y, acc[i][1]); \
    acc[i][2] = fmaf(xv, w0.z, acc[i][2]); acc[i][3] = fmaf(xv, w0.w, acc[i][3]); \
    acc[i][4] = fmaf(xv, w1.x, acc[i][4]); acc[i][5] = fmaf(xv, w1.y, acc[i][5]); \
    acc[i][6] = fmaf(xv, w1.z, acc[i][6]); acc[i][7] = fmaf(xv, w1.w, acc[i][7]);

__global__ __launch_bounds__(256, 4) void color_exact_k(
    const float* __restrict__ input, const float* __restrict__ wct,
    const float* __restrict__ tc, const float* __restrict__ Sc,
    unsigned long long* __restrict__ bc)
{
    __shared__ __align__(16) char smem[32768];
    float (*xs2)[16][128] = reinterpret_cast<float(*)[16][128]>(smem);
    float (*ws2)[16][128] = reinterpret_cast<float(*)[16][128]>(smem + 16384);

    int d = blockIdx.x;
    int o = (d & 7) * 128 + (d >> 3);
    int rowblk = o >> 2, cb = o & 3;
    int c0 = cb << 7;
    int tid = threadIdx.x;
    int lane = tid & 63;
    int wv = __builtin_amdgcn_readfirstlane(tid >> 6);
    int r0 = rowblk << 7;
    int b = r0 >> 10, hw0 = r0 & 1023;

    const float* __restrict__ xg =
        input + ((size_t)b << 18) + ((size_t)HALF << 10) + hw0
              + ((size_t)(lane >> 5) << 10) + ((lane & 31) << 2);
    const float* __restrict__ wg =
        wct + (size_t)(lane >> 5) * 512 + c0 + ((lane & 31) << 2);

    int tr = tid & 15, tcg = tid >> 4;
    int tr4 = tr << 2, tc4 = tcg << 2;
    int kw = wv << 2;

    float acc[8][8] = {{0.f}};

    #pragma unroll
    for (int i = 0; i < 2; ++i) {
        int kx = kw + (i << 1);
        __builtin_amdgcn_global_load_lds(
            (gbl_u32*)(xg + ((size_t)kx << 10)), (lds_u32*)&xs2[0][kx][0], 16, 0, 0);
        __builtin_amdgcn_global_load_lds(
            (gbl_u32*)(wg + (size_t)kx * 512), (lds_u32*)&ws2[0][kx][0], 16, 0, 0);
    }
    __syncthreads();

    for (int s = 0; s < 8; ++s) {
        if (s < 7) {
            int k0 = (s + 1) << 4;
            #pragma unroll
            for (int i = 0; i < 2; ++i) {
                int kx = kw + (i << 1);
                __builtin_amdgcn_global_load_lds(
                    (gbl_u32*)(xg + ((size_t)(k0 + kx) << 10)),
                    (lds_u32*)&xs2[(s + 1) & 1][kx][0], 16, 0, 0);
                __builtin_amdgcn_global_load_lds(
                    (gbl_u32*)(wg + (size_t)(k0 + kx) * 512),
                    (lds_u32*)&ws2[(s + 1) & 1][kx][0], 16, 0, 0);
            }
        }
        const float (*xsb)[128] = xs2[s & 1];
        const float (*wtb)[128] = ws2[s & 1];
        #pragma unroll 8
        for (int k = 0; k < 16; ++k) {
            const float4 x0 = *(const float4*)&xsb[k][tr4];
            const float4 x1 = *(const float4*)&xsb[k][64 + tr4];
            const float4 w0 = *(const float4*)&wtb[k][tc4];
            const float4 w1 = *(const float4*)&wtb[k][64 + tc4];
            FMA_ROW(0, x0.x) FMA_ROW(1, x0.y) FMA_ROW(2, x0.z) FMA_ROW(3, x0.w)
            FMA_ROW(4, x1.x) FMA_ROW(5, x1.y) FMA_ROW(6, x1.z) FMA_ROW(7, x1.w)
        }
        __syncthreads();
    }

    float Sr[8];
    #pragma unroll
    for (int i = 0; i < 8; ++i) {
        int rl = ((i & 4) << 4) + tr4 + (i & 3);
        Sr[i] = Sc[r0 + rl];
    }
    float bestD[8]; int bestC[8];
    #pragma unroll
    for (int i = 0; i < 8; ++i) { bestD[i] = INFINITY; bestC[i] = 0; }
    #pragma unroll
    for (int j = 0; j < 8; ++j) {
        int cl = ((j & 4) << 4) + tc4 + (j & 3);
        int cgj = c0 + cl;
        float tj = tc[cgj];
        #pragma unroll
        for (int i = 0; i < 8; ++i) {
            float Sp = Sr[i] + tj;
            float D = fmaf(-2.0f, acc[i][j], Sp);
            if (D < bestD[i]) { bestD[i] = D; bestC[i] = cgj; }
        }
    }
    __syncthreads();
    unsigned long long* red = reinterpret_cast<unsigned long long*>(smem);
    #pragma unroll
    for (int i = 0; i < 8; ++i) {
        int rl = ((i & 4) << 4) + tr4 + (i & 3);
        red[rl * 17 + tcg] =
            ((unsigned long long)mono_f32(bestD[i]) << 32) | (unsigned)bestC[i];
    }
    __syncthreads();
    if (tid < 128) {
        unsigned long long m = red[tid * 17];
        #pragma unroll
        for (int q = 1; q < 16; ++q) {
            unsigned long long v = red[tid * 17 + q];
            if (v < m) m = v;
        }
        atomicMin(&bc[r0 + tid], m);
    }
}

// ---- exact recheck of shape candidates (proven fp32 pipeline) ----
__global__ __launch_bounds__(256) void recheck_k(
    const float* __restrict__ input, const float* __restrict__ Ws,
    const float* __restrict__ ts, const float* __restrict__ Ss,
    const unsigned* __restrict__ rcS, const unsigned short* __restrict__ candS,
    unsigned long long* __restrict__ bs)
{
    __shared__ float xsh[32][132];
    int r0b = blockIdx.x << 5;
    int tid = threadIdx.x;
    int b = r0b >> 10, hw0 = r0b & 1023;
    for (int pass = 0; pass < 16; ++pass) {
        int k = pass * 8 + (tid >> 5), rl = tid & 31;
        xsh[rl][k] = input[((size_t)b << 18) + ((size_t)k << 10) + hw0 + rl];
    }
    __syncthreads();
    int g = tid >> 3, j8 = tid & 7;
    int r = r0b + g;
    unsigned n = rcS[r];
    bool full = (n == 0u) || (n > CAPS);
    int ne = full ? NSHAPE : (int)n;
    float Sv = Ss[r];
    const float4* x4 = (const float4*)&xsh[g][0];
    unsigned long long best = ~0ull;
    for (int c = j8; c < ne; c += 8) {
        int code = full ? c : (int)candS[(size_t)r * CAPS + c];
        const float4* w4 = (const float4*)(Ws + ((size_t)code << 7));
        float a = 0.f;
        #pragma unroll
        for (int q = 0; q < 32; ++q) {      // serial ascending-k fp32 chain
            float4 xq = x4[q];
            float4 wq = w4[q];
            a = fmaf(xq.x, wq.x, a); a = fmaf(xq.y, wq.y, a);
            a = fmaf(xq.z, wq.z, a); a = fmaf(xq.w, wq.w, a);
        }
        float D = fmaf(-2.0f, a, Sv + ts[code]);
        unsigned long long p = ((unsigned long long)mono_f32(D) << 32) | (unsigned)code;
        if (p < best) best = p;
    }
    #pragma unroll
    for (int m = 1; m < 8; m <<= 1) {
        unsigned long long v = __shfl_xor(best, m, 64);
        if (v < best) best = v;
    }
    if (j8 == 0) bs[r] = best;
}

__global__ __launch_bounds__(256) void finalize_k(
    const float* __restrict__ input,
    const float* __restrict__ Ws, const float* __restrict__ Wc,
    const unsigned long long* __restrict__ bs,
    const unsigned long long* __restrict__ bc,
    unsigned* __restrict__ cnt_s, unsigned* __restrict__ cnt_c,
    double* __restrict__ loss_sum, float* __restrict__ out)
{
    int tid = threadIdx.x;
    int r = blockIdx.x * 256 + tid;
    int bi = (int)(bs[r] & 0xFFFFFFFFu);
    int ci = (int)(bc[r] & 0xFFFFFFFFu);
    atomicAdd(&cnt_s[bi], 1u);
    atomicAdd(&cnt_c[ci], 1u);

    int b = r >> 10; int hw = r & 1023;
    const float* __restrict__ xin = input + ((size_t)b << 18) + hw;
    float* __restrict__ op = out + ((size_t)b << 18) + hw;
    const float* __restrict__ qs = Ws + ((size_t)bi << 7);
    const float* __restrict__ qc = Wc + ((size_t)ci << 7);

    double ls = 0.0;
    #pragma unroll 8
    for (int c = 0; c < HALF; ++c) {
        float f = xin[(size_t)c << 10];
        float dd = qs[c] - f;                  // fp32(q - f)
        op[(size_t)c << 10] = f + dd;          // fp32(f + fp32(q - f))
        ls += (double)dd * (double)dd;
    }
    #pragma unroll 8
    for (int c = 0; c < HALF; ++c) {
        float f = xin[(size_t)(c + HALF) << 10];
        float dd = qc[c] - f;
        op[(size_t)(c + HALF) << 10] = f + dd;
        ls += (double)dd * (double)dd;
    }
    __shared__ double red[256];
    red[tid] = ls;
    __syncthreads();
    for (int s = 128; s > 0; s >>= 1) {
        if (tid < s) red[tid] += red[tid + s];
        __syncthreads();
    }
    if (tid == 0) atomicAdd(loss_sum, red[0]);
}

__global__ __launch_bounds__(256) void scalars_k(
    const unsigned* __restrict__ cnt_s, const unsigned* __restrict__ cnt_c,
    const double* __restrict__ loss_sum, float* __restrict__ out3)
{
    int tid = threadIdx.x;
    double es = 0.0, ec = 0.0;
    for (int j = tid; j < NSHAPE; j += 256) {
        float p = (float)cnt_s[j] / 32768.0f;
        es += (double)(p * logf(p + 1e-10f));
    }
    for (int j = tid; j < NCOLOR; j += 256) {
        float p = (float)cnt_c[j] / 32768.0f;
        ec += (double)(p * logf(p + 1e-10f));
    }
    __shared__ double r1[256], r2[256];
    r1[tid] = es; r2[tid] = ec;
    __syncthreads();
    for (int s = 128; s > 0; s >>= 1) {
        if (tid < s) { r1[tid] += r1[tid + s]; r2[tid] += r2[tid + s]; }
        __syncthreads();
    }
    if (tid == 0) {
        out3[0] = (float)(1.25 * loss_sum[0] / 8388608.0);
        out3[1] = expf(-(float)r1[0]);
        out3[2] = expf(-(float)r2[0]);
    }
}

extern "C" void kernel_launch(void* const* d_in, const int* in_sizes, int n_in,
                              void* d_out, int out_size, void* d_ws, size_t ws_size,
                              hipStream_t stream)
{
    const float* input = (const float*)d_in[0];
    const float* Ws    = (const float*)d_in[1];
    const float* Wc    = (const float*)d_in[2];
    float* out = (float*)d_out;
    char* ws = (char*)d_ws;
    char* ob = (char*)d_out;

    float*    ts       = (float*)(ws + OFF_TS);
    float*    tcx      = (float*)(ws + OFF_TC);
    unsigned* cnt_s    = (unsigned*)(ws + OFF_CNT_S);
    unsigned* cnt_c    = (unsigned*)(ws + OFF_CNT_C);
    double*   loss_sum = (double*)(ws + OFF_LOSS);
    float*    Ss       = (float*)(ws + OFF_SS);
    float*    Sc       = (float*)(ws + OFF_SC);
    unsigned long long* bs = (unsigned long long*)(ws + OFF_BS);
    unsigned long long* bc = (unsigned long long*)(ws + OFF_BC);

    unsigned short* xhi  = (unsigned short*)(ob + OX_HI);
    unsigned short* xlo  = (unsigned short*)(ob + OX_LO);
    unsigned short* whiG = (unsigned short*)(ob + OW_HI);
    unsigned short* wloG = (unsigned short*)(ob + OW_LO);
    unsigned short* candS = (unsigned short*)(ob + OC_S);
    float*          Wct   = (float*)(ob + OWCT);
    unsigned*       rcS   = (unsigned*)(ob + ORCS);

    hipMemsetAsync(ws + OFF_CNT_S, 0, (OFF_LOSS + 8u) - OFF_CNT_S, stream);
    hipMemsetAsync(ws + OFF_BS, 0xFF, OFF_WSEND - OFF_BS, stream);
    hipMemsetAsync(ob + ORCS, 0, 131072u, stream);

    prep_k<<<738, 256, 0, stream>>>(Ws, Wc, input, ts, tcx, Ss, Sc,
                                    whiG, wloG, Wct, xhi, xlo);

    approx_k<<<NBLK_A, 256, 0, stream>>>(xhi, xlo, whiG, wloG, ts, Ss, rcS, candS);

    color_exact_k<<<1024, 256, 0, stream>>>(input, Wct, tcx, Sc, bc);

    recheck_k<<<1024, 256, 0, stream>>>(input, Ws, ts, Ss, rcS, candS, bs);

    finalize_k<<<NROWS / 256, 256, 0, stream>>>(
        input, Ws, Wc, bs, bc, cnt_s, cnt_c, loss_sum, out);

    scalars_k<<<1, 256, 0, stream>>>(cnt_s, cnt_c, loss_sum, out + 8388608);
}

// Round 17
// 868.221 us; speedup vs baseline: 2.5150x; 2.0178x over previous
//
#include <hip/hip_runtime.h>
#include <hip/hip_bf16.h>
#include <math.h>

// FactorizedVectorQuantizer MI355X (gfx950) — FINAL: the R8 champion kernel.
// BK=16 dual-operand global_load_lds double-buffer at 32KB LDS (4 blocks/CU),
// 8x8 micro-tile, one barrier per slab with issue-early prefetch (full-slab
// prefetch distance). Measured: 866 us total, gemm 777 us, VALUBusy 86.5%,
// 1.11x the LDS-issue-bound floor (697 us). R9-R16 exploration (VMEM-W,
// 8x16 tiles, 3-wave budgets, bf16-split MFMA candidate filter) all lost to
// this structure; MFMA filter remains 2x slower due to an unresolved 7x
// HBM fetch amplification + drain-limited load concurrency.
//
// rows 32768, feats 256 = 128 shape + 128 color; codebooks 8192x128, 512x128.
// Bit-exact numpy pipeline: D = fmaf(-2, dot, S + t); dot and S are single
// serial ascending-k fp32 FMA chains; argmin = lowest index on ties via
// strict-< ascending scan + packed u64 atomicMin key (mono(D)<<32 | code).

#define NROWS   32768
#define NSHAPE  8192
#define NCOLOR  512
#define HALF    128
#define NCODES  8704                // 8192 + 512 transposed columns

#define NSB     16384               // 256 rowblks x 64 colblks (shape)
#define NCB     1024                // 256 rowblks x 4 colblks (color)
#define NBLKS   (NSB + NCB)         // 17408, divisible by 8

// workspace byte offsets (Wt lives in d_out scratch, not here)
#define OFF_TS    0u                // f32[8192]
#define OFF_TC    32768u            // f32[512]
#define OFF_CNT_S 34816u            // u32[8192]
#define OFF_CNT_C 67584u            // u32[512]
#define OFF_LOSS  69632u            // double
#define OFF_SS    69648u            // f32[32768]
#define OFF_SC    200720u           // f32[32768]
#define OFF_BS    331792u           // u64[32768] packed best (shape)
#define OFF_BC    593936u           // u64[32768] packed best (color)
#define OFF_END   856080u

typedef __attribute__((address_space(3))) unsigned int  lds_u32;
typedef __attribute__((address_space(1))) const unsigned int gbl_u32;

__device__ __forceinline__ unsigned mono_f32(float d) {
    unsigned u = __float_as_uint(d);
    return (u & 0x80000000u) ? ~u : (u | 0x80000000u);
}

// fused prep: codes_sq (34 blocks) | rows_sq (128 blocks) | W transpose (544)
__global__ __launch_bounds__(256) void prep_k(
    const float* __restrict__ Ws, const float* __restrict__ Wc,
    const float* __restrict__ input,
    float* __restrict__ ts, float* __restrict__ tc,
    float* __restrict__ Ss, float* __restrict__ Sc,
    float* __restrict__ Wt)
{
    __shared__ float tile[32][65];
    int blk = blockIdx.x, tid = threadIdx.x;
    if (blk < 34) {
        int j = blk * 256 + tid;            // 0..8703
        const float* w; int jl;
        if (j < NSHAPE) { w = Ws + (size_t)j * HALF; jl = j; }
        else            { w = Wc + (size_t)(j - NSHAPE) * HALF; jl = j - NSHAPE; }
        float s = 0.f;
        #pragma unroll
        for (int k = 0; k < HALF; ++k) s = fmaf(w[k], w[k], s);
        if (j < NSHAPE) ts[jl] = s; else tc[jl] = s;
    } else if (blk < 162) {
        int r = (blk - 34) * 256 + tid;
        int b = r >> 10, hw = r & 1023;
        const float* __restrict__ xin = input + ((size_t)b << 18) + hw;
        float s = 0.f;
        #pragma unroll
        for (int k = 0; k < HALF; ++k) {
            float v = xin[(size_t)k << 10];
            s = fmaf(v, v, s);
        }
        Ss[r] = s;
        float s2 = 0.f;
        #pragma unroll
        for (int k = 0; k < HALF; ++k) {
            float v = xin[(size_t)(k + HALF) << 10];
            s2 = fmaf(v, v, s2);
        }
        Sc[r] = s2;
    } else {
        int b2 = blk - 162;                 // 0..543
        int cblk = b2 % 136, kblk = b2 / 136;
        int c0 = cblk << 6, k0 = kblk << 5;
        const float* src; int cl0;
        if (c0 < NSHAPE) { src = Ws; cl0 = c0; } else { src = Wc; cl0 = c0 - NSHAPE; }
        int kk = tid & 31, cc = tid >> 5;
        #pragma unroll
        for (int p = 0; p < 8; ++p) {
            int c = cc + (p << 3);
            tile[kk][c] = src[(size_t)(cl0 + c) * HALF + k0 + kk];
        }
        __syncthreads();
        int c2 = tid & 63, kr0 = (tid >> 6) << 3;
        #pragma unroll
        for (int p = 0; p < 8; ++p) {
            int kr = kr0 + p;
            Wt[(size_t)(k0 + kr) * NCODES + c0 + c2] = tile[kr][c2];
        }
    }
}

#define FMA_ROW(i, xv) \
    acc[i][0] = fmaf(xv, w0.x, acc[i][0]); acc[i][1] = fmaf(xv, w0.y, acc[i][1]); \
    acc[i][2] = fmaf(xv, w0.z, acc[i][2]); acc[i][3] = fmaf(xv, w0.w, acc[i][3]); \
    acc[i][4] = fmaf(xv, w1.x, acc[i][4]); acc[i][5] = fmaf(xv, w1.y, acc[i][5]); \
    acc[i][6] = fmaf(xv, w1.z, acc[i][6]); acc[i][7] = fmaf(xv, w1.w, acc[i][7]);

__global__ __launch_bounds__(256, 4) void gemm_argmin_k(
    const float* __restrict__ input, const float* __restrict__ wtg,
    const float* __restrict__ ts, const float* __restrict__ tc,
    const float* __restrict__ Ss, const float* __restrict__ Sc,
    unsigned long long* __restrict__ bs, unsigned long long* __restrict__ bc)
{
    __shared__ __align__(16) char smem[32768];
    // [buf][16k][128] each 8KB: X at 0/8K, W at 16K/24K
    float (*xs2)[16][128] = reinterpret_cast<float(*)[16][128]>(smem);
    float (*ws2)[16][128] = reinterpret_cast<float(*)[16][128]>(smem + 16384);

    int d = blockIdx.x;
    int o = (d & 7) * (NBLKS / 8) + (d >> 3);   // bijective XCD swizzle

    int rowblk, c0w, cgb, featoff;
    const float* tv; const float* Sarr; unsigned long long* bestArr;
    if (o < NSB) {
        rowblk = o >> 6; int cb = o & 63;
        c0w = cb << 7; cgb = cb << 7; featoff = 0;
        tv = ts; Sarr = Ss; bestArr = bs;
    } else {
        int o2 = o - NSB;
        rowblk = o2 >> 2; int cb = o2 & 3;
        c0w = NSHAPE + (cb << 7); cgb = cb << 7; featoff = HALF;
        tv = tc; Sarr = Sc; bestArr = bc;
    }

    int tid = threadIdx.x;
    int lane = tid & 63;
    int wv = __builtin_amdgcn_readfirstlane(tid >> 6);   // wave id 0..3
    int r0 = rowblk << 7;
    int b = r0 >> 10, hw0 = r0 & 1023;

    // per-lane DMA source bases (one 16B chunk per lane; 1 inst = 2 k-rows)
    const float* __restrict__ xg =
        input + ((size_t)b << 18) + ((size_t)featoff << 10) + hw0
              + ((size_t)(lane >> 5) << 10) + ((lane & 31) << 2);
    const float* __restrict__ wg =
        wtg + (size_t)(lane >> 5) * NCODES + c0w + ((lane & 31) << 2);

    int tr = tid & 15, tcg = tid >> 4;
    int tr4 = tr << 2, tc4 = tcg << 2;
    int kw = wv << 2;   // this wave's 4 k-rows within a slab

    float acc[8][8] = {{0.f}};

    // ---- prologue: DMA slab 0 (X and W) into buffer 0 ----
    #pragma unroll
    for (int i = 0; i < 2; ++i) {
        int kx = kw + (i << 1);                          // wave-uniform
        __builtin_amdgcn_global_load_lds(
            (gbl_u32*)(xg + ((size_t)kx << 10)),
            (lds_u32*)&xs2[0][kx][0], 16, 0, 0);
        __builtin_amdgcn_global_load_lds(
            (gbl_u32*)(wg + (size_t)kx * NCODES),
            (lds_u32*)&ws2[0][kx][0], 16, 0, 0);
    }
    __syncthreads();

    for (int s = 0; s < 8; ++s) {
        // ---- issue DMA for slab s+1 into the other buffer (issue-early) ----
        if (s < 7) {
            int k0 = (s + 1) << 4;
            #pragma unroll
            for (int i = 0; i < 2; ++i) {
                int kx = kw + (i << 1);
                __builtin_amdgcn_global_load_lds(
                    (gbl_u32*)(xg + ((size_t)(k0 + kx) << 10)),
                    (lds_u32*)&xs2[(s + 1) & 1][kx][0], 16, 0, 0);
                __builtin_amdgcn_global_load_lds(
                    (gbl_u32*)(wg + (size_t)(k0 + kx) * NCODES),
                    (lds_u32*)&ws2[(s + 1) & 1][kx][0], 16, 0, 0);
            }
        }

        // ---- compute slab s: serial ascending-k FMA chains per acc[i][j] --
        const float (*xsb)[128] = xs2[s & 1];
        const float (*wtb)[128] = ws2[s & 1];
        #pragma unroll 8
        for (int k = 0; k < 16; ++k) {
            const float4 x0 = *(const float4*)&xsb[k][tr4];
            const float4 x1 = *(const float4*)&xsb[k][64 + tr4];
            const float4 w0 = *(const float4*)&wtb[k][tc4];
            const float4 w1 = *(const float4*)&wtb[k][64 + tc4];
            FMA_ROW(0, x0.x) FMA_ROW(1, x0.y) FMA_ROW(2, x0.z) FMA_ROW(3, x0.w)
            FMA_ROW(4, x1.x) FMA_ROW(5, x1.y) FMA_ROW(6, x1.z) FMA_ROW(7, x1.w)
        }

        // loads for s+1 were issued a full slab ago -> drain is cheap
        __syncthreads();
    }

    // ---- epilogue: per-thread float argmin (strict <, ascending cols) ----
    float Sr[8];
    #pragma unroll
    for (int i = 0; i < 8; ++i) {
        int rl = ((i & 4) << 4) + tr4 + (i & 3);
        Sr[i] = Sarr[r0 + rl];
    }
    float bestD[8]; int bestC[8];
    #pragma unroll
    for (int i = 0; i < 8; ++i) { bestD[i] = INFINITY; bestC[i] = 0; }
    #pragma unroll
    for (int j = 0; j < 8; ++j) {
        int cl = ((j & 4) << 4) + tc4 + (j & 3);
        int cgj = cgb + cl;
        float tj = tv[cgj];
        #pragma unroll
        for (int i = 0; i < 8; ++i) {
            float Sp = Sr[i] + tj;
            float D = fmaf(-2.0f, acc[i][j], Sp);   // == Sp - 2*a bitwise
            if (D < bestD[i]) { bestD[i] = D; bestC[i] = cgj; }
        }
    }

    __syncthreads();   // tiles dead; reuse smem as reduction grid [128][17] u64
    unsigned long long* red = reinterpret_cast<unsigned long long*>(smem);
    #pragma unroll
    for (int i = 0; i < 8; ++i) {
        int rl = ((i & 4) << 4) + tr4 + (i & 3);
        red[rl * 17 + tcg] =
            ((unsigned long long)mono_f32(bestD[i]) << 32) | (unsigned)bestC[i];
    }
    __syncthreads();
    if (tid < 128) {
        unsigned long long m = red[tid * 17];
        #pragma unroll
        for (int q = 1; q < 16; ++q) {
            unsigned long long v = red[tid * 17 + q];
            if (v < m) m = v;
        }
        atomicMin(&bestArr[r0 + tid], m);
    }
}

__global__ __launch_bounds__(256) void finalize_k(
    const float* __restrict__ input,
    const float* __restrict__ Ws, const float* __restrict__ Wc,
    const unsigned long long* __restrict__ bs,
    const unsigned long long* __restrict__ bc,
    unsigned* __restrict__ cnt_s, unsigned* __restrict__ cnt_c,
    double* __restrict__ loss_sum, float* __restrict__ out)
{
    int tid = threadIdx.x;
    int r = blockIdx.x * 256 + tid;

    int bi = (int)(bs[r] & 0xFFFFFFFFu);
    int ci = (int)(bc[r] & 0xFFFFFFFFu);
    atomicAdd(&cnt_s[bi], 1u);
    atomicAdd(&cnt_c[ci], 1u);

    int b = r >> 10; int hw = r & 1023;
    const float* __restrict__ xin = input + ((size_t)b << 18) + hw;
    float* __restrict__ op = out + ((size_t)b << 18) + hw;
    const float* __restrict__ qs = Ws + ((size_t)bi << 7);
    const float* __restrict__ qc = Wc + ((size_t)ci << 7);

    double ls = 0.0;
    #pragma unroll 8
    for (int c = 0; c < HALF; ++c) {
        float f = xin[(size_t)c << 10];
        float dd = qs[c] - f;                  // fp32(q - f)
        op[(size_t)c << 10] = f + dd;          // fp32(f + fp32(q - f))
        ls += (double)dd * (double)dd;
    }
    #pragma unroll 8
    for (int c = 0; c < HALF; ++c) {
        float f = xin[(size_t)(c + HALF) << 10];
        float dd = qc[c] - f;
        op[(size_t)(c + HALF) << 10] = f + dd;
        ls += (double)dd * (double)dd;
    }

    __shared__ double red[256];
    red[tid] = ls;
    __syncthreads();
    for (int s = 128; s > 0; s >>= 1) {
        if (tid < s) red[tid] += red[tid + s];
        __syncthreads();
    }
    if (tid == 0) atomicAdd(loss_sum, red[0]);
}

__global__ __launch_bounds__(256) void scalars_k(
    const unsigned* __restrict__ cnt_s, const unsigned* __restrict__ cnt_c,
    const double* __restrict__ loss_sum, float* __restrict__ out3)
{
    int tid = threadIdx.x;
    double es = 0.0, ec = 0.0;
    for (int j = tid; j < NSHAPE; j += 256) {
        float p = (float)cnt_s[j] / 32768.0f;
        es += (double)(p * logf(p + 1e-10f));
    }
    for (int j = tid; j < NCOLOR; j += 256) {
        float p = (float)cnt_c[j] / 32768.0f;
        ec += (double)(p * logf(p + 1e-10f));
    }
    __shared__ double r1[256], r2[256];
    r1[tid] = es; r2[tid] = ec;
    __syncthreads();
    for (int s = 128; s > 0; s >>= 1) {
        if (tid < s) { r1[tid] += r1[tid + s]; r2[tid] += r2[tid + s]; }
        __syncthreads();
    }
    if (tid == 0) {
        out3[0] = (float)(1.25 * loss_sum[0] / 8388608.0);  // q + 0.25*e latent
        out3[1] = expf(-(float)r1[0]);
        out3[2] = expf(-(float)r2[0]);
    }
}

extern "C" void kernel_launch(void* const* d_in, const int* in_sizes, int n_in,
                              void* d_out, int out_size, void* d_ws, size_t ws_size,
                              hipStream_t stream)
{
    const float* input = (const float*)d_in[0];
    const float* Ws    = (const float*)d_in[1];
    const float* Wc    = (const float*)d_in[2];
    float* out = (float*)d_out;
    char* ws = (char*)d_ws;

    float*    ts       = (float*)(ws + OFF_TS);
    float*    tcx      = (float*)(ws + OFF_TC);
    unsigned* cnt_s    = (unsigned*)(ws + OFF_CNT_S);
    unsigned* cnt_c    = (unsigned*)(ws + OFF_CNT_C);
    double*   loss_sum = (double*)(ws + OFF_LOSS);
    float*    Ss       = (float*)(ws + OFF_SS);
    float*    Sc       = (float*)(ws + OFF_SC);
    unsigned long long* bs = (unsigned long long*)(ws + OFF_BS);
    unsigned long long* bc = (unsigned long long*)(ws + OFF_BC);

    // Wt[128][8704] lives in d_out (finalize_k fully overwrites d_out later)
    float* Wt = out;

    // counts + loss: zero.  best arrays: 0xFF (== u64 max sentinel).
    hipMemsetAsync(ws + OFF_CNT_S, 0, (OFF_LOSS + 8u) - OFF_CNT_S, stream);
    hipMemsetAsync(ws + OFF_BS, 0xFF, OFF_END - OFF_BS, stream);

    prep_k<<<706, 256, 0, stream>>>(Ws, Wc, input, ts, tcx, Ss, Sc, Wt);

    gemm_argmin_k<<<NBLKS, 256, 0, stream>>>(
        input, Wt, ts, tcx, Ss, Sc, bs, bc);

    finalize_k<<<NROWS / 256, 256, 0, stream>>>(
        input, Ws, Wc, bs, bc, cnt_s, cnt_c, loss_sum, out);

    scalars_k<<<1, 256, 0, stream>>>(cnt_s, cnt_c, loss_sum, out + 8388608);
}